// Round 8
// baseline (222.234 us; speedup 1.0000x reference)
//
#include <hip/hip_runtime.h>
#include <math.h>

#define INF_ 100000.0f
constexpr int B_ = 64, W_ = 16, T_ = 64, U_ = 128, S_ = 20, N_ = 8;

typedef unsigned short ushort_t;
typedef __attribute__((ext_vector_type(8))) short bf16x8;
typedef __attribute__((ext_vector_type(4))) float floatx4;

static __device__ __forceinline__ unsigned short f2bf(float x) {
    unsigned int u = __float_as_uint(x);
    return (unsigned short)((u + 0x7fff + ((u >> 16) & 1)) >> 16);  // RNE
}
static __device__ __forceinline__ float bf2f(unsigned short s) {
    return __uint_as_float(((unsigned int)s) << 16);
}

// ---------------------------------------------------------------------------
// K0: cast/transpose prep (adds c_bf: 32x128, rows >=20 zeroed).
// ---------------------------------------------------------------------------
__global__ __launch_bounds__(256) void k0_cast(
    const float* __restrict__ q_status, const float* __restrict__ weight,
    const float* __restrict__ W1, const float* __restrict__ W2,
    const float* __restrict__ c,
    ushort_t* __restrict__ qstat_bf, ushort_t* __restrict__ wcomb,
    ushort_t* __restrict__ w1botT, ushort_t* __restrict__ w2T,
    ushort_t* __restrict__ c_bf)
{
    int idx = blockIdx.x * 256 + threadIdx.x;
    if (idx < 1048576) { qstat_bf[idx] = f2bf(q_status[idx]); return; }
    idx -= 1048576;
    if (idx < 32768) {
        int j = idx >> 7, k = idx & 127;
        float v = (j < 128) ? weight[k * 128 + j] : W1[k * 128 + (j - 128)];
        wcomb[idx] = f2bf(v); return;
    }
    idx -= 32768;
    if (idx < 16384) {
        int j = idx >> 7, k = idx & 127;
        w1botT[idx] = f2bf(W1[(128 + k) * 128 + j]); return;
    }
    idx -= 16384;
    if (idx < 16384) {
        int j = idx >> 7, k = idx & 127;
        w2T[idx] = f2bf(W2[k * 128 + j]); return;
    }
    idx -= 16384;
    if (idx < 4096) {
        int s = idx >> 7;
        c_bf[idx] = (s < 20) ? f2bf(c[idx]) : (ushort_t)0;
        return;
    }
}

// ---------------------------------------------------------------------------
// K1 (MFMA): per bw: sc = c@h^T -> softmax(t) -> q_slot = P@h + pos (bf16 out)
// sh_c dropped (A-frags from global c_bf, L2-hot): LDS 49.2 KB -> 3 blk/CU.
// ---------------------------------------------------------------------------
__global__ __launch_bounds__(256) void k1_attn(
    const float* __restrict__ h,        // [B,W,64,128]
    const ushort_t* __restrict__ c_bf,  // [32][128] rows>=20 zero
    const float* __restrict__ pos,      // [B,W,20,128]
    ushort_t* __restrict__ q_slot_bf)   // [B*W*20][128]
{
    __shared__ __align__(16) ushort_t sh_h[64 * 136];    // [t][u]
    __shared__ __align__(16) ushort_t sh_hT[128 * 72];   // [u][t]
    __shared__ __align__(16) float    sh_sc[32 * 68];    // scores
    __shared__ __align__(16) ushort_t sh_P[32 * 72];     // [s][t] (rows>=20 zero)

    const int bw = blockIdx.x, tid = threadIdx.x;
    const float* hb = h + (size_t)bw * 8192;
    for (int i = tid; i < 8192; i += 256) {
        int t = i >> 7, u = i & 127;
        ushort_t v = f2bf(hb[i]);
        sh_h[t * 136 + u] = v;
        sh_hT[u * 72 + t] = v;
    }
    for (int i = tid; i < 32 * 72; i += 256) sh_P[i] = 0;
    __syncthreads();

    const int wave = tid >> 6, lane = tid & 63, m16 = lane & 15, q = lane >> 4;

    // GEMM1: sc[s][t]: 2 mt x 4 jt, wave does 2 combos; A from global c_bf
#pragma unroll
    for (int ci = 0; ci < 2; ++ci) {
        int cmb = wave * 2 + ci;
        int mt = cmb >> 2, jt = cmb & 3;
        floatx4 acc = {0.f, 0.f, 0.f, 0.f};
#pragma unroll
        for (int kt = 0; kt < 4; ++kt) {
            bf16x8 a = *(const bf16x8*)&c_bf[(mt * 16 + m16) * 128 + kt * 32 + q * 8];
            bf16x8 b = *(const bf16x8*)&sh_h[(jt * 16 + m16) * 136 + kt * 32 + q * 8];
            acc = __builtin_amdgcn_mfma_f32_16x16x32_bf16(a, b, acc, 0, 0, 0);
        }
#pragma unroll
        for (int reg = 0; reg < 4; ++reg)
            sh_sc[(mt * 16 + q * 4 + reg) * 68 + jt * 16 + m16] = acc[reg];
    }
    __syncthreads();

    // softmax over t (wave per row)
    for (int s = wave; s < 20; s += 4) {
        float v = sh_sc[s * 68 + lane];
        if (v == 0.0f) v = -INF_;
        float m = v;
        for (int d = 32; d; d >>= 1) m = fmaxf(m, __shfl_xor(m, d));
        float e = expf(v - m);
        float sum = e;
        for (int d = 32; d; d >>= 1) sum += __shfl_xor(sum, d);
        sh_P[s * 72 + lane] = f2bf(e / sum);
    }
    __syncthreads();

    // GEMM2: q_slot = P@h + pos
    const size_t obase = (size_t)bw * 2560;
#pragma unroll
    for (int ci = 0; ci < 4; ++ci) {
        int cmb = wave * 4 + ci;
        int mt = cmb >> 3, jt = cmb & 7;
        floatx4 acc = {0.f, 0.f, 0.f, 0.f};
#pragma unroll
        for (int kt = 0; kt < 2; ++kt) {
            bf16x8 a = *(const bf16x8*)&sh_P[(mt * 16 + m16) * 72 + kt * 32 + q * 8];
            bf16x8 b = *(const bf16x8*)&sh_hT[(jt * 16 + m16) * 72 + kt * 32 + q * 8];
            acc = __builtin_amdgcn_mfma_f32_16x16x32_bf16(a, b, acc, 0, 0, 0);
        }
        int u = jt * 16 + m16;
#pragma unroll
        for (int reg = 0; reg < 4; ++reg) {
            int row = mt * 16 + q * 4 + reg;
            if (row < 20)
                q_slot_bf[obase + row * 128 + u] =
                    f2bf(acc[reg] + pos[obase + row * 128 + u]);
        }
    }
}

// ---------------------------------------------------------------------------
// K2ab (fused): blocks 0..159 = k2a ([qw|A] = q_slot @ wcomb, 128 rows/blk);
// blocks 160..223 = k2b (QS1^T store, 128 rows/blk).  512 threads.
// ---------------------------------------------------------------------------
__global__ __launch_bounds__(512, 2) void k2ab(
    const ushort_t* __restrict__ qs_bf,     // [20480][128]
    const ushort_t* __restrict__ wcomb,     // [256][128] (j-major)
    const float* __restrict__ b1,
    const ushort_t* __restrict__ qstat_bf,  // [8192][128]
    const ushort_t* __restrict__ w1botT,    // [128][128] (j-major)
    ushort_t* __restrict__ qw_bf,           // [20480][128]
    float* __restrict__ A,                  // [20480][128]
    ushort_t* __restrict__ qs1T_bf)         // [B][128 u][128 xn]
{
    __shared__ __align__(16) ushort_t sh_w[256 * 136];
    const int tid = threadIdx.x;
    const int wave = tid >> 6, lane = tid & 63, m16 = lane & 15, q = lane >> 4;

    if (blockIdx.x < 160) {
        // ---- k2a role ----
        for (int i = tid * 4; i < 32768; i += 2048) {
            int j = i >> 7, k = i & 127;
            *(ushort4*)&sh_w[j * 136 + k] = *(const ushort4*)&wcomb[i];
        }
        __syncthreads();

        const size_t row = (size_t)blockIdx.x * 128 + wave * 16 + m16;
        floatx4 acc[16];
#pragma unroll
        for (int jt = 0; jt < 16; ++jt) acc[jt] = (floatx4){0.f, 0.f, 0.f, 0.f};
#pragma unroll
        for (int kt = 0; kt < 4; ++kt) {
            bf16x8 a = *(const bf16x8*)&qs_bf[row * 128 + kt * 32 + q * 8];
#pragma unroll
            for (int jt = 0; jt < 16; ++jt) {
                bf16x8 b = *(const bf16x8*)&sh_w[(jt * 16 + m16) * 136 + kt * 32 + q * 8];
                acc[jt] = __builtin_amdgcn_mfma_f32_16x16x32_bf16(a, b, acc[jt], 0, 0, 0);
            }
        }
        const size_t orow0 = (size_t)blockIdx.x * 128 + wave * 16 + q * 4;
#pragma unroll
        for (int jt = 0; jt < 16; ++jt) {
            int col = jt * 16 + m16;
            if (col < 128) {
#pragma unroll
                for (int reg = 0; reg < 4; ++reg)
                    qw_bf[(orow0 + reg) * 128 + col] = f2bf(acc[jt][reg]);
            } else {
                float bv = b1[col - 128];
#pragma unroll
                for (int reg = 0; reg < 4; ++reg)
                    A[(orow0 + reg) * 128 + (col - 128)] = acc[jt][reg] + bv;
            }
        }
    } else {
        // ---- k2b role ----
        const int blk = blockIdx.x - 160;
        for (int i = tid * 4; i < 16384; i += 2048) {
            int j = i >> 7, k = i & 127;
            *(ushort4*)&sh_w[j * 136 + k] = *(const ushort4*)&w1botT[i];
        }
        __syncthreads();

        const size_t row = (size_t)blk * 128 + wave * 16 + m16;
        floatx4 acc[8];
#pragma unroll
        for (int jt = 0; jt < 8; ++jt) acc[jt] = (floatx4){0.f, 0.f, 0.f, 0.f};
#pragma unroll
        for (int kt = 0; kt < 4; ++kt) {
            bf16x8 a = *(const bf16x8*)&qstat_bf[row * 128 + kt * 32 + q * 8];
#pragma unroll
            for (int jt = 0; jt < 8; ++jt) {
                bf16x8 b = *(const bf16x8*)&sh_w[(jt * 16 + m16) * 136 + kt * 32 + q * 8];
                acc[jt] = __builtin_amdgcn_mfma_f32_16x16x32_bf16(a, b, acc[jt], 0, 0, 0);
            }
        }
        const size_t orow0 = (size_t)blk * 128 + wave * 16 + q * 4;
#pragma unroll
        for (int jt = 0; jt < 8; ++jt) {
            int col = jt * 16 + m16;                 // u
#pragma unroll
            for (int reg = 0; reg < 4; ++reg) {
                size_t grow = orow0 + reg;           // global xn-row = b*128 + xn
                qs1T_bf[(grow >> 7) * 16384 + (size_t)col * 128 + (grow & 127)]
                    = f2bf(acc[jt][reg]);
            }
        }
    }
}

// ---------------------------------------------------------------------------
// K3 (MFMA): co[b] = qw[b] @ qstat[b]^T, bf16 out.  grid (5, 64).
// ---------------------------------------------------------------------------
__global__ __launch_bounds__(256) void k3_co(
    const ushort_t* __restrict__ qw_bf,
    const ushort_t* __restrict__ qstat_bf,
    ushort_t* __restrict__ co_bf)        // [B][320][128] bf16
{
    __shared__ __align__(16) ushort_t sh_y[128 * 136];
    const int tid = threadIdx.x, rt = blockIdx.x, b = blockIdx.y;
    for (int i = tid * 4; i < 16384; i += 1024) {
        int j = i >> 7, k = i & 127;
        *(ushort4*)&sh_y[j * 136 + k] = *(const ushort4*)&qstat_bf[(size_t)b * 16384 + i];
    }
    __syncthreads();

    const int wave = tid >> 6, lane = tid & 63, m16 = lane & 15, q = lane >> 4;
    const size_t rbase = (size_t)b * 320 + rt * 64 + wave * 16;

    floatx4 acc[8];
#pragma unroll
    for (int jt = 0; jt < 8; ++jt) acc[jt] = (floatx4){0.f, 0.f, 0.f, 0.f};
#pragma unroll
    for (int kt = 0; kt < 4; ++kt) {
        bf16x8 a = *(const bf16x8*)&qw_bf[(rbase + m16) * 128 + kt * 32 + q * 8];
#pragma unroll
        for (int jt = 0; jt < 8; ++jt) {
            bf16x8 b2_ = *(const bf16x8*)&sh_y[(jt * 16 + m16) * 136 + kt * 32 + q * 8];
            acc[jt] = __builtin_amdgcn_mfma_f32_16x16x32_bf16(a, b2_, acc[jt], 0, 0, 0);
        }
    }
#pragma unroll
    for (int jt = 0; jt < 8; ++jt)
#pragma unroll
        for (int reg = 0; reg < 4; ++reg)
            co_bf[(rbase + q * 4 + reg) * 128 + jt * 16 + m16] = f2bf(acc[jt][reg]);
}

// ---------------------------------------------------------------------------
// K4 (fully-MFMA fused): sh_w2t dropped -> h2 B-frags straight from global
// w2T (identical across 1024 blocks -> L2-hot).  LDS = sh_u only (43.5 KB),
// halving the per-wave ds_read_b128 count.  Softmax over all 640 threads.
// ---------------------------------------------------------------------------
__global__ __launch_bounds__(640, 5) void k4_fused(
    const ushort_t* __restrict__ co_bf,    // [B][320][128] bf16
    const ushort_t* __restrict__ qs1T_bf,  // [B][128 u][128 xn]
    const float* __restrict__ A,           // [B*W*20][128]
    const ushort_t* __restrict__ w2T,      // [128][128] (j-major)
    const float* __restrict__ b2,
    const float* __restrict__ W3,
    const float* __restrict__ b3,
    float* __restrict__ lg)                // [B*W][160]
{
    __shared__ __align__(16) ushort_t sh_u[160 * 136];    // 43520 B union:
    // phase A: rows 0..127 = qs1T [u][xn]; [17408 + s*132 + xn] = p2
    // phase B: [row_sn*136 + u] = h1 (bf16)

    const int bw = blockIdx.x, b = bw >> 4, tid = threadIdx.x;

    for (int i = tid * 4; i < 16384; i += 2560)
        *(ushort4*)&sh_u[(i >> 7) * 136 + (i & 127)] =
            *(const ushort4*)&qs1T_bf[(size_t)b * 16384 + i];

    // softmax over x, all 640 threads: sn = tid>>2, xi = tid&3 (4 x each)
    {
        int sn = tid >> 2, xi = tid & 3;
        int s = sn >> 3, n = sn & 7;
        const ushort_t* crow = co_bf + ((size_t)bw * 20 + s) * 128;
        float v[4];
        float m = -INFINITY;
#pragma unroll
        for (int j = 0; j < 4; ++j) {
            float t = bf2f(crow[(xi + 4 * j) * 8 + n]);
            if (t == 0.0f) t = -INF_;
            v[j] = t;
            m = fmaxf(m, t);
        }
        m = fmaxf(m, __shfl_xor(m, 1));
        m = fmaxf(m, __shfl_xor(m, 2));
        float sum = 0.f;
#pragma unroll
        for (int j = 0; j < 4; ++j) { v[j] = expf(v[j] - m); sum += v[j]; }
        sum += __shfl_xor(sum, 1);
        sum += __shfl_xor(sum, 2);
        float r = 1.0f / sum;
#pragma unroll
        for (int j = 0; j < 4; ++j)
            sh_u[17408 + s * 132 + (xi + 4 * j) * 8 + n] = f2bf(v[j] * r);
    }
    __syncthreads();

    const int wave = tid >> 6, lane = tid & 63, m16 = lane & 15, q = lane >> 4;
    const int n = m16 & 7;
    const int sIdx = wave * 2 + (m16 >> 3);
    const int rowS = wave * 16 + m16;

    // ---- h1^T MFMA ----
    floatx4 gacc[8];
#pragma unroll
    for (int mt = 0; mt < 8; ++mt) gacc[mt] = (floatx4){0.f, 0.f, 0.f, 0.f};

#pragma unroll
    for (int kt = 0; kt < 4; ++kt) {
        short pv = (short)sh_u[17408 + sIdx * 132 + kt * 32 + q * 8 + n];
        bf16x8 pf = {0, 0, 0, 0, 0, 0, 0, 0};
        pf[0] = (n == 0) ? pv : (short)0;
        pf[1] = (n == 1) ? pv : (short)0;
        pf[2] = (n == 2) ? pv : (short)0;
        pf[3] = (n == 3) ? pv : (short)0;
        pf[4] = (n == 4) ? pv : (short)0;
        pf[5] = (n == 5) ? pv : (short)0;
        pf[6] = (n == 6) ? pv : (short)0;
        pf[7] = (n == 7) ? pv : (short)0;
#pragma unroll
        for (int mt = 0; mt < 8; ++mt) {
            bf16x8 af = *(const bf16x8*)&sh_u[(mt * 16 + m16) * 136 + kt * 32 + q * 8];
            gacc[mt] = __builtin_amdgcn_mfma_f32_16x16x32_bf16(af, pf, gacc[mt], 0, 0, 0);
        }
    }
    __syncthreads();   // qs1T/p2 reads done; union region may be rewritten

    // ---- h1 = relu(gacc + A[s][u]) -> bf16 in LDS ----
    {
        const float* Ab = A + ((size_t)bw * 20 + sIdx) * 128;
#pragma unroll
        for (int mt = 0; mt < 8; ++mt) {
            int u0 = mt * 16 + q * 4;
            float4 av = *(const float4*)&Ab[u0];
            ushort4 o;
            o.x = f2bf(fmaxf(gacc[mt][0] + av.x, 0.f));
            o.y = f2bf(fmaxf(gacc[mt][1] + av.y, 0.f));
            o.z = f2bf(fmaxf(gacc[mt][2] + av.z, 0.f));
            o.w = f2bf(fmaxf(gacc[mt][3] + av.w, 0.f));
            *(ushort4*)&sh_u[rowS * 136 + u0] = o;
        }
    }
    __syncthreads();

    // ---- h2 GEMM: B-frags from global w2T (L2-hot) ----
    floatx4 acc[8];
#pragma unroll
    for (int jt = 0; jt < 8; ++jt) acc[jt] = (floatx4){0.f, 0.f, 0.f, 0.f};

#pragma unroll
    for (int kt = 0; kt < 4; ++kt) {
        const int k0 = kt * 32 + q * 8;
        bf16x8 af = *(const bf16x8*)&sh_u[rowS * 136 + k0];
#pragma unroll
        for (int jt = 0; jt < 8; ++jt) {
            bf16x8 bfr = *(const bf16x8*)&w2T[(jt * 16 + m16) * 128 + k0];
            acc[jt] = __builtin_amdgcn_mfma_f32_16x16x32_bf16(af, bfr, acc[jt], 0, 0, 0);
        }
    }

    float b2v[8], w3v[8];
#pragma unroll
    for (int jt = 0; jt < 8; ++jt) {
        b2v[jt] = b2[jt * 16 + m16];
        w3v[jt] = W3[jt * 16 + m16];
    }
    const float b3v = b3[0];

#pragma unroll
    for (int reg = 0; reg < 4; ++reg) {
        float p = 0.f;
#pragma unroll
        for (int jt = 0; jt < 8; ++jt)
            p += fmaxf(acc[jt][reg] + b2v[jt], 0.f) * w3v[jt];
        p += __shfl_xor(p, 1);
        p += __shfl_xor(p, 2);
        p += __shfl_xor(p, 4);
        p += __shfl_xor(p, 8);
        if (m16 == 0)
            lg[(size_t)bw * 160 + wave * 16 + q * 4 + reg] = p + b3v;
    }
}

// ---------------------------------------------------------------------------
// K5: masked max over W, labels, scalar.
// ---------------------------------------------------------------------------
__global__ __launch_bounds__(256) void k5_final(
    const float* __restrict__ lg,
    const float* __restrict__ mask,
    float* __restrict__ out)
{
    int idx = blockIdx.x * 256 + threadIdx.x;
    const int SN = S_ * N_;
    if (idx < B_ * SN) {
        int b = idx / SN, sn = idx % SN;
        float m = -INFINITY;
        for (int w = 0; w < W_; ++w) {
            float v = lg[((size_t)b * W_ + w) * SN + sn] + mask[((size_t)b * W_ + w) * SN + sn];
            m = fmaxf(m, v);
        }
        out[idx] = (m > 0.f) ? 1.f : 0.f;
        out[B_ * SN + 1 + idx] = m;
    }
    if (idx == 0) out[B_ * SN] = (float)SN;
}

// ---------------------------------------------------------------------------
extern "C" void kernel_launch(void* const* d_in, const int* in_sizes, int n_in,
                              void* d_out, int out_size, void* d_ws, size_t ws_size,
                              hipStream_t stream) {
    const float* slot_utt_h = (const float*)d_in[0];
    const float* slot_candidate_c = (const float*)d_in[1];
    const float* position_encoding = (const float*)d_in[3];
    const float* q_status = (const float*)d_in[4];
    const float* mask = (const float*)d_in[5];
    const float* weight = (const float*)d_in[6];
    const float* W1 = (const float*)d_in[7];
    const float* b1 = (const float*)d_in[8];
    const float* W2 = (const float*)d_in[9];
    const float* b2 = (const float*)d_in[10];
    const float* W3 = (const float*)d_in[11];
    const float* b3 = (const float*)d_in[12];
    float* out = (float*)d_out;

    float* f = (float*)d_ws;
    ushort_t* q_slot_bf = (ushort_t*)(f + 0);        // 2,621,440 sh
    ushort_t* qw_bf     = (ushort_t*)(f + 1310720);  // 2,621,440 sh
    float*    A         = f + 2621440;               // 2,621,440 f
    ushort_t* qs1T_bf   = (ushort_t*)(f + 5242880);  // 1,048,576 sh
    ushort_t* co_bf     = (ushort_t*)(f + 5767168);  // 2,621,440 sh (bf16 now)
    float*    lg        = f + 8388608;               //   163,840 f
    ushort_t* qstat_bf  = (ushort_t*)(f + 8552448);  // 1,048,576 sh
    ushort_t* wcomb     = (ushort_t*)(f + 9076736);  //    32,768 sh
    ushort_t* w1botT    = (ushort_t*)(f + 9093120);  //    16,384 sh
    ushort_t* w2T       = (ushort_t*)(f + 9101312);  //    16,384 sh
    ushort_t* c_bf      = (ushort_t*)(f + 9109504);  //     4,096 sh

    k0_cast<<<4368, 256, 0, stream>>>(q_status, weight, W1, W2,
                                      slot_candidate_c,
                                      qstat_bf, wcomb, w1botT, w2T, c_bf);
    k1_attn<<<1024, 256, 0, stream>>>(slot_utt_h, c_bf,
                                      position_encoding, q_slot_bf);
    k2ab<<<224, 512, 0, stream>>>(q_slot_bf, wcomb, b1, qstat_bf, w1botT,
                                  qw_bf, A, qs1T_bf);
    k3_co<<<dim3(5, 64), 256, 0, stream>>>(qw_bf, qstat_bf, co_bf);
    k4_fused<<<1024, 640, 0, stream>>>(co_bf, qs1T_bf, A, w2T, b2, W3, b3, lg);
    k5_final<<<(B_ * S_ * N_ + 255) / 256, 256, 0, stream>>>(lg, mask, out);
}

// Round 9
// 179.148 us; speedup vs baseline: 1.2405x; 1.2405x over previous
//
#include <hip/hip_runtime.h>
#include <math.h>

#define INF_ 100000.0f
constexpr int B_ = 64, W_ = 16, T_ = 64, U_ = 128, S_ = 20, N_ = 8;

typedef unsigned short ushort_t;
typedef __attribute__((ext_vector_type(8))) short bf16x8;
typedef __attribute__((ext_vector_type(4))) float floatx4;

static __device__ __forceinline__ unsigned short f2bf(float x) {
    unsigned int u = __float_as_uint(x);
    return (unsigned short)((u + 0x7fff + ((u >> 16) & 1)) >> 16);  // RNE
}
static __device__ __forceinline__ float bf2f(unsigned short s) {
    return __uint_as_float(((unsigned int)s) << 16);
}

// ---------------------------------------------------------------------------
// K0: cast/transpose prep (c_bf: 32x128, rows >=20 zeroed).
// ---------------------------------------------------------------------------
__global__ __launch_bounds__(256) void k0_cast(
    const float* __restrict__ q_status, const float* __restrict__ weight,
    const float* __restrict__ W1, const float* __restrict__ W2,
    const float* __restrict__ c,
    ushort_t* __restrict__ qstat_bf, ushort_t* __restrict__ wcomb,
    ushort_t* __restrict__ w1botT, ushort_t* __restrict__ w2T,
    ushort_t* __restrict__ c_bf)
{
    int idx = blockIdx.x * 256 + threadIdx.x;
    if (idx < 1048576) { qstat_bf[idx] = f2bf(q_status[idx]); return; }
    idx -= 1048576;
    if (idx < 32768) {
        int j = idx >> 7, k = idx & 127;
        float v = (j < 128) ? weight[k * 128 + j] : W1[k * 128 + (j - 128)];
        wcomb[idx] = f2bf(v); return;
    }
    idx -= 32768;
    if (idx < 16384) {
        int j = idx >> 7, k = idx & 127;
        w1botT[idx] = f2bf(W1[(128 + k) * 128 + j]); return;
    }
    idx -= 16384;
    if (idx < 16384) {
        int j = idx >> 7, k = idx & 127;
        w2T[idx] = f2bf(W2[k * 128 + j]); return;
    }
    idx -= 16384;
    if (idx < 4096) {
        int s = idx >> 7;
        c_bf[idx] = (s < 20) ? f2bf(c[idx]) : (ushort_t)0;
        return;
    }
}

// ---------------------------------------------------------------------------
// K1 (MFMA): per bw: sc = c@h^T -> softmax(t) -> q_slot = P@h + pos (bf16 out)
// sh_c dropped (A-frags from global c_bf, L2-hot; outside inner loop it's one
// load per ci/kt — acceptable): LDS 49.2 KB -> 3 blk/CU.
// ---------------------------------------------------------------------------
__global__ __launch_bounds__(256) void k1_attn(
    const float* __restrict__ h,        // [B,W,64,128]
    const ushort_t* __restrict__ c_bf,  // [32][128] rows>=20 zero
    const float* __restrict__ pos,      // [B,W,20,128]
    ushort_t* __restrict__ q_slot_bf)   // [B*W*20][128]
{
    __shared__ __align__(16) ushort_t sh_h[64 * 136];    // [t][u]
    __shared__ __align__(16) ushort_t sh_hT[128 * 72];   // [u][t]
    __shared__ __align__(16) float    sh_sc[32 * 68];    // scores
    __shared__ __align__(16) ushort_t sh_P[32 * 72];     // [s][t] (rows>=20 zero)

    const int bw = blockIdx.x, tid = threadIdx.x;
    const float* hb = h + (size_t)bw * 8192;
    for (int i = tid; i < 8192; i += 256) {
        int t = i >> 7, u = i & 127;
        ushort_t v = f2bf(hb[i]);
        sh_h[t * 136 + u] = v;
        sh_hT[u * 72 + t] = v;
    }
    for (int i = tid; i < 32 * 72; i += 256) sh_P[i] = 0;
    __syncthreads();

    const int wave = tid >> 6, lane = tid & 63, m16 = lane & 15, q = lane >> 4;

    // GEMM1: sc[s][t]: 2 mt x 4 jt, wave does 2 combos; A from global c_bf
#pragma unroll
    for (int ci = 0; ci < 2; ++ci) {
        int cmb = wave * 2 + ci;
        int mt = cmb >> 2, jt = cmb & 3;
        floatx4 acc = {0.f, 0.f, 0.f, 0.f};
#pragma unroll
        for (int kt = 0; kt < 4; ++kt) {
            bf16x8 a = *(const bf16x8*)&c_bf[(mt * 16 + m16) * 128 + kt * 32 + q * 8];
            bf16x8 b = *(const bf16x8*)&sh_h[(jt * 16 + m16) * 136 + kt * 32 + q * 8];
            acc = __builtin_amdgcn_mfma_f32_16x16x32_bf16(a, b, acc, 0, 0, 0);
        }
#pragma unroll
        for (int reg = 0; reg < 4; ++reg)
            sh_sc[(mt * 16 + q * 4 + reg) * 68 + jt * 16 + m16] = acc[reg];
    }
    __syncthreads();

    // softmax over t (wave per row)
    for (int s = wave; s < 20; s += 4) {
        float v = sh_sc[s * 68 + lane];
        if (v == 0.0f) v = -INF_;
        float m = v;
        for (int d = 32; d; d >>= 1) m = fmaxf(m, __shfl_xor(m, d));
        float e = expf(v - m);
        float sum = e;
        for (int d = 32; d; d >>= 1) sum += __shfl_xor(sum, d);
        sh_P[s * 72 + lane] = f2bf(e / sum);
    }
    __syncthreads();

    // GEMM2: q_slot = P@h + pos
    const size_t obase = (size_t)bw * 2560;
#pragma unroll
    for (int ci = 0; ci < 4; ++ci) {
        int cmb = wave * 4 + ci;
        int mt = cmb >> 3, jt = cmb & 7;
        floatx4 acc = {0.f, 0.f, 0.f, 0.f};
#pragma unroll
        for (int kt = 0; kt < 2; ++kt) {
            bf16x8 a = *(const bf16x8*)&sh_P[(mt * 16 + m16) * 72 + kt * 32 + q * 8];
            bf16x8 b = *(const bf16x8*)&sh_hT[(jt * 16 + m16) * 72 + kt * 32 + q * 8];
            acc = __builtin_amdgcn_mfma_f32_16x16x32_bf16(a, b, acc, 0, 0, 0);
        }
        int u = jt * 16 + m16;
#pragma unroll
        for (int reg = 0; reg < 4; ++reg) {
            int row = mt * 16 + q * 4 + reg;
            if (row < 20)
                q_slot_bf[obase + row * 128 + u] =
                    f2bf(acc[reg] + pos[obase + row * 128 + u]);
        }
    }
}

// ---------------------------------------------------------------------------
// K2ab (fused): blocks 0..159 = k2a ([qw|A] = q_slot @ wcomb, 128 rows/blk);
// blocks 160..223 = k2b (QS1^T store, 128 rows/blk).  512 threads.
// ---------------------------------------------------------------------------
__global__ __launch_bounds__(512, 2) void k2ab(
    const ushort_t* __restrict__ qs_bf,     // [20480][128]
    const ushort_t* __restrict__ wcomb,     // [256][128] (j-major)
    const float* __restrict__ b1,
    const ushort_t* __restrict__ qstat_bf,  // [8192][128]
    const ushort_t* __restrict__ w1botT,    // [128][128] (j-major)
    ushort_t* __restrict__ qw_bf,           // [20480][128]
    float* __restrict__ A,                  // [20480][128]
    ushort_t* __restrict__ qs1T_bf)         // [B][128 u][128 xn]
{
    __shared__ __align__(16) ushort_t sh_w[256 * 136];
    const int tid = threadIdx.x;
    const int wave = tid >> 6, lane = tid & 63, m16 = lane & 15, q = lane >> 4;

    if (blockIdx.x < 160) {
        for (int i = tid * 4; i < 32768; i += 2048) {
            int j = i >> 7, k = i & 127;
            *(ushort4*)&sh_w[j * 136 + k] = *(const ushort4*)&wcomb[i];
        }
        __syncthreads();

        const size_t row = (size_t)blockIdx.x * 128 + wave * 16 + m16;
        floatx4 acc[16];
#pragma unroll
        for (int jt = 0; jt < 16; ++jt) acc[jt] = (floatx4){0.f, 0.f, 0.f, 0.f};
#pragma unroll
        for (int kt = 0; kt < 4; ++kt) {
            bf16x8 a = *(const bf16x8*)&qs_bf[row * 128 + kt * 32 + q * 8];
#pragma unroll
            for (int jt = 0; jt < 16; ++jt) {
                bf16x8 b = *(const bf16x8*)&sh_w[(jt * 16 + m16) * 136 + kt * 32 + q * 8];
                acc[jt] = __builtin_amdgcn_mfma_f32_16x16x32_bf16(a, b, acc[jt], 0, 0, 0);
            }
        }
        const size_t orow0 = (size_t)blockIdx.x * 128 + wave * 16 + q * 4;
#pragma unroll
        for (int jt = 0; jt < 16; ++jt) {
            int col = jt * 16 + m16;
            if (col < 128) {
#pragma unroll
                for (int reg = 0; reg < 4; ++reg)
                    qw_bf[(orow0 + reg) * 128 + col] = f2bf(acc[jt][reg]);
            } else {
                float bv = b1[col - 128];
#pragma unroll
                for (int reg = 0; reg < 4; ++reg)
                    A[(orow0 + reg) * 128 + (col - 128)] = acc[jt][reg] + bv;
            }
        }
    } else {
        const int blk = blockIdx.x - 160;
        for (int i = tid * 4; i < 16384; i += 2048) {
            int j = i >> 7, k = i & 127;
            *(ushort4*)&sh_w[j * 136 + k] = *(const ushort4*)&w1botT[i];
        }
        __syncthreads();

        const size_t row = (size_t)blk * 128 + wave * 16 + m16;
        floatx4 acc[8];
#pragma unroll
        for (int jt = 0; jt < 8; ++jt) acc[jt] = (floatx4){0.f, 0.f, 0.f, 0.f};
#pragma unroll
        for (int kt = 0; kt < 4; ++kt) {
            bf16x8 a = *(const bf16x8*)&qstat_bf[row * 128 + kt * 32 + q * 8];
#pragma unroll
            for (int jt = 0; jt < 8; ++jt) {
                bf16x8 b = *(const bf16x8*)&sh_w[(jt * 16 + m16) * 136 + kt * 32 + q * 8];
                acc[jt] = __builtin_amdgcn_mfma_f32_16x16x32_bf16(a, b, acc[jt], 0, 0, 0);
            }
        }
        const size_t orow0 = (size_t)blk * 128 + wave * 16 + q * 4;
#pragma unroll
        for (int jt = 0; jt < 8; ++jt) {
            int col = jt * 16 + m16;                 // u
#pragma unroll
            for (int reg = 0; reg < 4; ++reg) {
                size_t grow = orow0 + reg;           // global xn-row = b*128 + xn
                qs1T_bf[(grow >> 7) * 16384 + (size_t)col * 128 + (grow & 127)]
                    = f2bf(acc[jt][reg]);
            }
        }
    }
}

// ---------------------------------------------------------------------------
// K3 (MFMA): co[b] = qw[b] @ qstat[b]^T, bf16 out.  grid (5, 64).
// ---------------------------------------------------------------------------
__global__ __launch_bounds__(256) void k3_co(
    const ushort_t* __restrict__ qw_bf,
    const ushort_t* __restrict__ qstat_bf,
    ushort_t* __restrict__ co_bf)        // [B][320][128] bf16
{
    __shared__ __align__(16) ushort_t sh_y[128 * 136];
    const int tid = threadIdx.x, rt = blockIdx.x, b = blockIdx.y;
    for (int i = tid * 4; i < 16384; i += 1024) {
        int j = i >> 7, k = i & 127;
        *(ushort4*)&sh_y[j * 136 + k] = *(const ushort4*)&qstat_bf[(size_t)b * 16384 + i];
    }
    __syncthreads();

    const int wave = tid >> 6, lane = tid & 63, m16 = lane & 15, q = lane >> 4;
    const size_t rbase = (size_t)b * 320 + rt * 64 + wave * 16;

    floatx4 acc[8];
#pragma unroll
    for (int jt = 0; jt < 8; ++jt) acc[jt] = (floatx4){0.f, 0.f, 0.f, 0.f};
#pragma unroll
    for (int kt = 0; kt < 4; ++kt) {
        bf16x8 a = *(const bf16x8*)&qw_bf[(rbase + m16) * 128 + kt * 32 + q * 8];
#pragma unroll
        for (int jt = 0; jt < 8; ++jt) {
            bf16x8 b2_ = *(const bf16x8*)&sh_y[(jt * 16 + m16) * 136 + kt * 32 + q * 8];
            acc[jt] = __builtin_amdgcn_mfma_f32_16x16x32_bf16(a, b2_, acc[jt], 0, 0, 0);
        }
    }
#pragma unroll
    for (int jt = 0; jt < 8; ++jt)
#pragma unroll
        for (int reg = 0; reg < 4; ++reg)
            co_bf[(rbase + q * 4 + reg) * 128 + jt * 16 + m16] = f2bf(acc[jt][reg]);
}

// ---------------------------------------------------------------------------
// K4 (fully-MFMA fused, R7 structure restored): ALL MFMA operands from LDS.
// R8 lesson: B-frags from global in the inner loop -> vmcnt-drain
// latency-serialization (75 us, everything idle).  sh_w2t back in LDS.
// ---------------------------------------------------------------------------
__global__ __launch_bounds__(640, 5) void k4_fused(
    const ushort_t* __restrict__ co_bf,    // [B][320][128] bf16
    const ushort_t* __restrict__ qs1T_bf,  // [B][128 u][128 xn]
    const float* __restrict__ A,           // [B*W*20][128]
    const ushort_t* __restrict__ w2T,      // [128][128] (j-major)
    const float* __restrict__ b2,
    const float* __restrict__ W3,
    const float* __restrict__ b3,
    float* __restrict__ lg)                // [B*W][160]
{
    __shared__ __align__(16) ushort_t sh_w2t[128 * 136];  // 34816 B
    __shared__ __align__(16) ushort_t sh_u[160 * 136];    // 43520 B union:
    // phase A: rows 0..127 = qs1T [u][xn]; [17408 + s*132 + xn] = p2
    // phase B: [row_sn*136 + u] = h1 (bf16)

    const int bw = blockIdx.x, b = bw >> 4, tid = threadIdx.x;

    for (int i = tid * 4; i < 16384; i += 2560) {
        int r = i >> 7, k = i & 127;
        *(ushort4*)&sh_w2t[r * 136 + k] = *(const ushort4*)&w2T[i];
        *(ushort4*)&sh_u[r * 136 + k] =
            *(const ushort4*)&qs1T_bf[(size_t)b * 16384 + i];
    }

    // softmax over x, all 640 threads: sn = tid>>2, xi = tid&3 (4 x each)
    {
        int sn = tid >> 2, xi = tid & 3;
        int s = sn >> 3, n = sn & 7;
        const ushort_t* crow = co_bf + ((size_t)bw * 20 + s) * 128;
        float v[4];
        float m = -INFINITY;
#pragma unroll
        for (int j = 0; j < 4; ++j) {
            float t = bf2f(crow[(xi + 4 * j) * 8 + n]);
            if (t == 0.0f) t = -INF_;
            v[j] = t;
            m = fmaxf(m, t);
        }
        m = fmaxf(m, __shfl_xor(m, 1));
        m = fmaxf(m, __shfl_xor(m, 2));
        float sum = 0.f;
#pragma unroll
        for (int j = 0; j < 4; ++j) { v[j] = expf(v[j] - m); sum += v[j]; }
        sum += __shfl_xor(sum, 1);
        sum += __shfl_xor(sum, 2);
        float r = 1.0f / sum;
#pragma unroll
        for (int j = 0; j < 4; ++j)
            sh_u[17408 + s * 132 + (xi + 4 * j) * 8 + n] = f2bf(v[j] * r);
    }
    __syncthreads();

    const int wave = tid >> 6, lane = tid & 63, m16 = lane & 15, q = lane >> 4;
    const int n = m16 & 7;
    const int sIdx = wave * 2 + (m16 >> 3);
    const int rowS = wave * 16 + m16;

    // ---- h1^T MFMA (A-frags + synthesized sparse B-frags, all LDS) ----
    floatx4 gacc[8];
#pragma unroll
    for (int mt = 0; mt < 8; ++mt) gacc[mt] = (floatx4){0.f, 0.f, 0.f, 0.f};

#pragma unroll
    for (int kt = 0; kt < 4; ++kt) {
        short pv = (short)sh_u[17408 + sIdx * 132 + kt * 32 + q * 8 + n];
        bf16x8 pf = {0, 0, 0, 0, 0, 0, 0, 0};
        pf[0] = (n == 0) ? pv : (short)0;
        pf[1] = (n == 1) ? pv : (short)0;
        pf[2] = (n == 2) ? pv : (short)0;
        pf[3] = (n == 3) ? pv : (short)0;
        pf[4] = (n == 4) ? pv : (short)0;
        pf[5] = (n == 5) ? pv : (short)0;
        pf[6] = (n == 6) ? pv : (short)0;
        pf[7] = (n == 7) ? pv : (short)0;
#pragma unroll
        for (int mt = 0; mt < 8; ++mt) {
            bf16x8 af = *(const bf16x8*)&sh_u[(mt * 16 + m16) * 136 + kt * 32 + q * 8];
            gacc[mt] = __builtin_amdgcn_mfma_f32_16x16x32_bf16(af, pf, gacc[mt], 0, 0, 0);
        }
    }
    __syncthreads();   // qs1T/p2 reads done; union region may be rewritten

    // ---- h1 = relu(gacc + A[s][u]) -> bf16 in LDS ----
    {
        const float* Ab = A + ((size_t)bw * 20 + sIdx) * 128;
#pragma unroll
        for (int mt = 0; mt < 8; ++mt) {
            int u0 = mt * 16 + q * 4;
            float4 av = *(const float4*)&Ab[u0];
            ushort4 o;
            o.x = f2bf(fmaxf(gacc[mt][0] + av.x, 0.f));
            o.y = f2bf(fmaxf(gacc[mt][1] + av.y, 0.f));
            o.z = f2bf(fmaxf(gacc[mt][2] + av.z, 0.f));
            o.w = f2bf(fmaxf(gacc[mt][3] + av.w, 0.f));
            *(ushort4*)&sh_u[rowS * 136 + u0] = o;
        }
    }
    __syncthreads();

    // ---- h2 GEMM: wave owns row-tile 'wave'; B-frags from LDS sh_w2t ----
    floatx4 acc[8];
#pragma unroll
    for (int jt = 0; jt < 8; ++jt) acc[jt] = (floatx4){0.f, 0.f, 0.f, 0.f};

#pragma unroll
    for (int kt = 0; kt < 4; ++kt) {
        const int k0 = kt * 32 + q * 8;
        bf16x8 af = *(const bf16x8*)&sh_u[rowS * 136 + k0];
#pragma unroll
        for (int jt = 0; jt < 8; ++jt) {
            bf16x8 bfr = *(const bf16x8*)&sh_w2t[(jt * 16 + m16) * 136 + k0];
            acc[jt] = __builtin_amdgcn_mfma_f32_16x16x32_bf16(af, bfr, acc[jt], 0, 0, 0);
        }
    }

    float b2v[8], w3v[8];
#pragma unroll
    for (int jt = 0; jt < 8; ++jt) {
        b2v[jt] = b2[jt * 16 + m16];
        w3v[jt] = W3[jt * 16 + m16];
    }
    const float b3v = b3[0];

#pragma unroll
    for (int reg = 0; reg < 4; ++reg) {
        float p = 0.f;
#pragma unroll
        for (int jt = 0; jt < 8; ++jt)
            p += fmaxf(acc[jt][reg] + b2v[jt], 0.f) * w3v[jt];
        p += __shfl_xor(p, 1);
        p += __shfl_xor(p, 2);
        p += __shfl_xor(p, 4);
        p += __shfl_xor(p, 8);
        if (m16 == 0)
            lg[(size_t)bw * 160 + wave * 16 + q * 4 + reg] = p + b3v;
    }
}

// ---------------------------------------------------------------------------
// K5: masked max over W, labels, scalar.
// ---------------------------------------------------------------------------
__global__ __launch_bounds__(256) void k5_final(
    const float* __restrict__ lg,
    const float* __restrict__ mask,
    float* __restrict__ out)
{
    int idx = blockIdx.x * 256 + threadIdx.x;
    const int SN = S_ * N_;
    if (idx < B_ * SN) {
        int b = idx / SN, sn = idx % SN;
        float m = -INFINITY;
        for (int w = 0; w < W_; ++w) {
            float v = lg[((size_t)b * W_ + w) * SN + sn] + mask[((size_t)b * W_ + w) * SN + sn];
            m = fmaxf(m, v);
        }
        out[idx] = (m > 0.f) ? 1.f : 0.f;
        out[B_ * SN + 1 + idx] = m;
    }
    if (idx == 0) out[B_ * SN] = (float)SN;
}

// ---------------------------------------------------------------------------
extern "C" void kernel_launch(void* const* d_in, const int* in_sizes, int n_in,
                              void* d_out, int out_size, void* d_ws, size_t ws_size,
                              hipStream_t stream) {
    const float* slot_utt_h = (const float*)d_in[0];
    const float* slot_candidate_c = (const float*)d_in[1];
    const float* position_encoding = (const float*)d_in[3];
    const float* q_status = (const float*)d_in[4];
    const float* mask = (const float*)d_in[5];
    const float* weight = (const float*)d_in[6];
    const float* W1 = (const float*)d_in[7];
    const float* b1 = (const float*)d_in[8];
    const float* W2 = (const float*)d_in[9];
    const float* b2 = (const float*)d_in[10];
    const float* W3 = (const float*)d_in[11];
    const float* b3 = (const float*)d_in[12];
    float* out = (float*)d_out;

    float* f = (float*)d_ws;
    ushort_t* q_slot_bf = (ushort_t*)(f + 0);        // 2,621,440 sh
    ushort_t* qw_bf     = (ushort_t*)(f + 1310720);  // 2,621,440 sh
    float*    A         = f + 2621440;               // 2,621,440 f
    ushort_t* qs1T_bf   = (ushort_t*)(f + 5242880);  // 1,048,576 sh
    ushort_t* co_bf     = (ushort_t*)(f + 5767168);  // 2,621,440 sh
    float*    lg        = f + 8388608;               //   163,840 f
    ushort_t* qstat_bf  = (ushort_t*)(f + 8552448);  // 1,048,576 sh
    ushort_t* wcomb     = (ushort_t*)(f + 9076736);  //    32,768 sh
    ushort_t* w1botT    = (ushort_t*)(f + 9093120);  //    16,384 sh
    ushort_t* w2T       = (ushort_t*)(f + 9101312);  //    16,384 sh
    ushort_t* c_bf      = (ushort_t*)(f + 9109504);  //     4,096 sh

    k0_cast<<<4368, 256, 0, stream>>>(q_status, weight, W1, W2,
                                      slot_candidate_c,
                                      qstat_bf, wcomb, w1botT, w2T, c_bf);
    k1_attn<<<1024, 256, 0, stream>>>(slot_utt_h, c_bf,
                                      position_encoding, q_slot_bf);
    k2ab<<<224, 512, 0, stream>>>(q_slot_bf, wcomb, b1, qstat_bf, w1botT,
                                  qw_bf, A, qs1T_bf);
    k3_co<<<dim3(5, 64), 256, 0, stream>>>(qw_bf, qstat_bf, co_bf);
    k4_fused<<<1024, 640, 0, stream>>>(co_bf, qs1T_bf, A, w2T, b2, W3, b3, lg);
    k5_final<<<(B_ * S_ * N_ + 255) / 256, 256, 0, stream>>>(lg, mask, out);
}